// Round 3
// baseline (229.052 us; speedup 1.0000x reference)
//
#include <hip/hip_runtime.h>

constexpr int HW = 1024 * 1024;
constexpr int NB = 16;
constexpr float EPS = 1e-6f;
constexpr int BLOCKS_PER_BATCH = 256;  // 4096 blocks total
constexpr int THREADS = 256;
constexpr int NVEC    = HW / 4;                      // 262144 vec4 per batch
constexpr int TPB     = BLOCKS_PER_BATCH * THREADS;  // 65536 threads per batch
constexpr int U       = NVEC / TPB;                  // 4 windows per thread (exact)
constexpr int NBLK    = NB * BLOCKS_PER_BATCH;       // 4096

typedef float f32x4 __attribute__((ext_vector_type(4)));
typedef int   i32x4 __attribute__((ext_vector_type(4)));

// Stage 1: per-block partials -> ws4[gid] = {Sp, Spp, St, Stp}. No atomics.
//
// R2 proved the forced 12-deep pipeline (all loads issued up front into
// named registers + sched_barrier) covers the memory latency. R3 flips ONE
// variable vs R2: nontemporal -> plain cached loads. R1's counters showed
// FETCH_SIZE = 98 MB with plain loads (half the 201 MB input survives in the
// 256 MB Infinity Cache across bench iterations); nt-loads skip L3 retention
// and force the full 201 MB from HBM every iteration.
__global__ __launch_bounds__(THREADS, 6) void dice_partial(
        const float* __restrict__ logits,
        const int*   __restrict__ labels,
        f32x4*       __restrict__ ws4) {
    const int b   = blockIdx.x >> 8;         // / BLOCKS_PER_BATCH
    const int blk = blockIdx.x & 255;        // % BLOCKS_PER_BATCH

    const f32x4* __restrict__ L0 = reinterpret_cast<const f32x4*>(logits + (size_t)b * 2 * HW);
    const f32x4* __restrict__ L1 = reinterpret_cast<const f32x4*>(logits + (size_t)b * 2 * HW + HW);
    const i32x4* __restrict__ LB = reinterpret_cast<const i32x4*>(labels + (size_t)b * HW);

    const int base = blk * THREADS + threadIdx.x;   // interleaved, window stride = TPB

    // Issue all 12 loads, window-major, so consumption of window u can
    // proceed at vmcnt(9/6/3/0) while later windows stay in flight.
    f32x4 a0 = L0[base + 0 * TPB];
    f32x4 c0 = L1[base + 0 * TPB];
    i32x4 t0 = LB[base + 0 * TPB];
    f32x4 a1 = L0[base + 1 * TPB];
    f32x4 c1 = L1[base + 1 * TPB];
    i32x4 t1 = LB[base + 1 * TPB];
    f32x4 a2 = L0[base + 2 * TPB];
    f32x4 c2 = L1[base + 2 * TPB];
    i32x4 t2 = LB[base + 2 * TPB];
    f32x4 a3 = L0[base + 3 * TPB];
    f32x4 c3 = L1[base + 3 * TPB];
    i32x4 t3 = LB[base + 3 * TPB];
    __builtin_amdgcn_sched_barrier(0);   // loads may not sink past this point

    float sp = 0.f, spp = 0.f, st = 0.f, stp = 0.f;

    #define CONSUME(A, C, T)                                              \
        _Pragma("unroll")                                                 \
        for (int k = 0; k < 4; ++k) {                                     \
            const float p  = 1.f / (1.f + __expf((A)[k] - (C)[k]));       \
            const float tf = (float)(T)[k];                               \
            sp += p; spp = fmaf(p, p, spp); st += tf; stp = fmaf(tf, p, stp); \
        }

    CONSUME(a0, c0, t0)
    CONSUME(a1, c1, t1)
    CONSUME(a2, c2, t2)
    CONSUME(a3, c3, t3)
    #undef CONSUME

    // wave-64 shuffle reduction
    #pragma unroll
    for (int off = 32; off > 0; off >>= 1) {
        sp  += __shfl_down(sp,  off);
        spp += __shfl_down(spp, off);
        st  += __shfl_down(st,  off);
        stp += __shfl_down(stp, off);
    }

    __shared__ float red[4][4];   // [wave][component]
    const int wave = threadIdx.x >> 6;
    const int lane = threadIdx.x & 63;
    if (lane == 0) {
        red[wave][0] = sp; red[wave][1] = spp; red[wave][2] = st; red[wave][3] = stp;
    }
    __syncthreads();
    if (threadIdx.x == 0) {
        f32x4 r;
        r.x = red[0][0] + red[1][0] + red[2][0] + red[3][0];
        r.y = red[0][1] + red[1][1] + red[2][1] + red[3][1];
        r.z = red[0][2] + red[1][2] + red[2][2] + red[3][2];
        r.w = red[0][3] + red[1][3] + red[2][3] + red[3][3];
        ws4[blockIdx.x] = r;   // plain store, distinct slot per block
    }
}

// Stage 2 (merged): one block, 1024 threads = 16 waves; wave w folds batch w's
// 256 partials and computes its dice term; thread 0 then folds the 16 terms.
__global__ __launch_bounds__(1024) void dice_reduce(
        const f32x4* __restrict__ ws4,
        float*       __restrict__ out) {
    const int wave = threadIdx.x >> 6;   // 0..15 == batch index
    const int lane = threadIdx.x & 63;

    const f32x4* p = ws4 + wave * BLOCKS_PER_BATCH;
    f32x4 v = p[lane] + p[lane + 64] + p[lane + 128] + p[lane + 192];

    #pragma unroll
    for (int off = 32; off > 0; off >>= 1) {
        v.x += __shfl_down(v.x, off);
        v.y += __shfl_down(v.y, off);
        v.z += __shfl_down(v.z, off);
        v.w += __shfl_down(v.w, off);
    }

    __shared__ float terms[NB];
    if (lane == 0) {
        const float Sp  = v.x;
        const float Spp = v.y;
        const float St  = v.z;
        const float Stp = v.w;
        const float N = (float)HW;

        const float num1 = 2.f * Stp;
        const float den1 = Spp + St;
        const float num0 = 2.f * (N - St - Sp + Stp);
        const float den0 = (N - 2.f * Sp + Spp) + (N - St);

        terms[wave] = num0 / (den0 + EPS) + num1 / (den1 + EPS);
    }
    __syncthreads();
    if (threadIdx.x == 0) {
        float s = 0.f;
        #pragma unroll
        for (int i = 0; i < NB; ++i) s += terms[i];
        out[0] = 1.f - s / 32.f;
    }
}

extern "C" void kernel_launch(void* const* d_in, const int* in_sizes, int n_in,
                              void* d_out, int out_size, void* d_ws, size_t ws_size,
                              hipStream_t stream) {
    const float* logits = (const float*)d_in[0];
    const int*   labels = (const int*)d_in[1];
    float* out = (float*)d_out;
    f32x4* ws4 = (f32x4*)d_ws;                       // 4096 vec4 = 64 KB

    dice_partial<<<NBLK, THREADS, 0, stream>>>(logits, labels, ws4);
    dice_reduce<<<1, 1024, 0, stream>>>(ws4, out);
}

// Round 4
// 219.153 us; speedup vs baseline: 1.0452x; 1.0452x over previous
//
#include <hip/hip_runtime.h>

constexpr int HW = 1024 * 1024;
constexpr int NB = 16;
constexpr float EPS = 1e-6f;
constexpr int BLOCKS_PER_BATCH = 256;  // 4096 blocks total
constexpr int THREADS = 256;
constexpr int NVEC    = HW / 4;                      // 262144 vec4 per batch
constexpr int TPB     = BLOCKS_PER_BATCH * THREADS;  // 65536 threads per batch
constexpr int U       = NVEC / TPB;                  // 4 windows per thread (exact)
constexpr int NBLK    = NB * BLOCKS_PER_BATCH;       // 4096

typedef float f32x4 __attribute__((ext_vector_type(4)));
typedef int   i32x4 __attribute__((ext_vector_type(4)));

// Stage 1: per-block partials -> ws4[gid] = {Sp, Spp, St, Stp}. No atomics.
//
// R2 (best, 214.7 us): nt loads + forced 12-deep pipeline. R3 (all-plain,
// 229 us): the L2-allocating path loses ~15 us when the 134 MB logits
// stream thrashes through it. R4 flips ONE variable vs R2: LABEL loads only
// become plain/cached. Rationale: R1's FETCH_SIZE=98 MB proved ~100 MB of
// input survives the poison fills in the 256 MB L3 (fills bypass LLC);
// the 67 MB label stream fits stably in L3 when it is the only allocating
// stream, supplying labels off the HBM path while logits stream nt.
__global__ __launch_bounds__(THREADS, 6) void dice_partial(
        const float* __restrict__ logits,
        const int*   __restrict__ labels,
        f32x4*       __restrict__ ws4) {
    const int b   = blockIdx.x >> 8;         // / BLOCKS_PER_BATCH
    const int blk = blockIdx.x & 255;        // % BLOCKS_PER_BATCH

    const f32x4* __restrict__ L0 = reinterpret_cast<const f32x4*>(logits + (size_t)b * 2 * HW);
    const f32x4* __restrict__ L1 = reinterpret_cast<const f32x4*>(logits + (size_t)b * 2 * HW + HW);
    const i32x4* __restrict__ LB = reinterpret_cast<const i32x4*>(labels + (size_t)b * HW);

    const int base = blk * THREADS + threadIdx.x;   // interleaved, window stride = TPB

    // Issue all 12 loads, window-major, so consumption of window u can
    // proceed at vmcnt(9/6/3/0) while later windows stay in flight.
    f32x4 a0 = __builtin_nontemporal_load(&L0[base + 0 * TPB]);
    f32x4 c0 = __builtin_nontemporal_load(&L1[base + 0 * TPB]);
    i32x4 t0 = LB[base + 0 * TPB];
    f32x4 a1 = __builtin_nontemporal_load(&L0[base + 1 * TPB]);
    f32x4 c1 = __builtin_nontemporal_load(&L1[base + 1 * TPB]);
    i32x4 t1 = LB[base + 1 * TPB];
    f32x4 a2 = __builtin_nontemporal_load(&L0[base + 2 * TPB]);
    f32x4 c2 = __builtin_nontemporal_load(&L1[base + 2 * TPB]);
    i32x4 t2 = LB[base + 2 * TPB];
    f32x4 a3 = __builtin_nontemporal_load(&L0[base + 3 * TPB]);
    f32x4 c3 = __builtin_nontemporal_load(&L1[base + 3 * TPB]);
    i32x4 t3 = LB[base + 3 * TPB];
    __builtin_amdgcn_sched_barrier(0);   // loads may not sink past this point

    float sp = 0.f, spp = 0.f, st = 0.f, stp = 0.f;

    #define CONSUME(A, C, T)                                              \
        _Pragma("unroll")                                                 \
        for (int k = 0; k < 4; ++k) {                                     \
            const float p  = 1.f / (1.f + __expf((A)[k] - (C)[k]));       \
            const float tf = (float)(T)[k];                               \
            sp += p; spp = fmaf(p, p, spp); st += tf; stp = fmaf(tf, p, stp); \
        }

    CONSUME(a0, c0, t0)
    CONSUME(a1, c1, t1)
    CONSUME(a2, c2, t2)
    CONSUME(a3, c3, t3)
    #undef CONSUME

    // wave-64 shuffle reduction
    #pragma unroll
    for (int off = 32; off > 0; off >>= 1) {
        sp  += __shfl_down(sp,  off);
        spp += __shfl_down(spp, off);
        st  += __shfl_down(st,  off);
        stp += __shfl_down(stp, off);
    }

    __shared__ float red[4][4];   // [wave][component]
    const int wave = threadIdx.x >> 6;
    const int lane = threadIdx.x & 63;
    if (lane == 0) {
        red[wave][0] = sp; red[wave][1] = spp; red[wave][2] = st; red[wave][3] = stp;
    }
    __syncthreads();
    if (threadIdx.x == 0) {
        f32x4 r;
        r.x = red[0][0] + red[1][0] + red[2][0] + red[3][0];
        r.y = red[0][1] + red[1][1] + red[2][1] + red[3][1];
        r.z = red[0][2] + red[1][2] + red[2][2] + red[3][2];
        r.w = red[0][3] + red[1][3] + red[2][3] + red[3][3];
        ws4[blockIdx.x] = r;   // plain store, distinct slot per block
    }
}

// Stage 2 (merged): one block, 1024 threads = 16 waves; wave w folds batch w's
// 256 partials and computes its dice term; thread 0 then folds the 16 terms.
__global__ __launch_bounds__(1024) void dice_reduce(
        const f32x4* __restrict__ ws4,
        float*       __restrict__ out) {
    const int wave = threadIdx.x >> 6;   // 0..15 == batch index
    const int lane = threadIdx.x & 63;

    const f32x4* p = ws4 + wave * BLOCKS_PER_BATCH;
    f32x4 v = p[lane] + p[lane + 64] + p[lane + 128] + p[lane + 192];

    #pragma unroll
    for (int off = 32; off > 0; off >>= 1) {
        v.x += __shfl_down(v.x, off);
        v.y += __shfl_down(v.y, off);
        v.z += __shfl_down(v.z, off);
        v.w += __shfl_down(v.w, off);
    }

    __shared__ float terms[NB];
    if (lane == 0) {
        const float Sp  = v.x;
        const float Spp = v.y;
        const float St  = v.z;
        const float Stp = v.w;
        const float N = (float)HW;

        const float num1 = 2.f * Stp;
        const float den1 = Spp + St;
        const float num0 = 2.f * (N - St - Sp + Stp);
        const float den0 = (N - 2.f * Sp + Spp) + (N - St);

        terms[wave] = num0 / (den0 + EPS) + num1 / (den1 + EPS);
    }
    __syncthreads();
    if (threadIdx.x == 0) {
        float s = 0.f;
        #pragma unroll
        for (int i = 0; i < NB; ++i) s += terms[i];
        out[0] = 1.f - s / 32.f;
    }
}

extern "C" void kernel_launch(void* const* d_in, const int* in_sizes, int n_in,
                              void* d_out, int out_size, void* d_ws, size_t ws_size,
                              hipStream_t stream) {
    const float* logits = (const float*)d_in[0];
    const int*   labels = (const int*)d_in[1];
    float* out = (float*)d_out;
    f32x4* ws4 = (f32x4*)d_ws;                       // 4096 vec4 = 64 KB

    dice_partial<<<NBLK, THREADS, 0, stream>>>(logits, labels, ws4);
    dice_reduce<<<1, 1024, 0, stream>>>(ws4, out);
}

// Round 5
// 215.087 us; speedup vs baseline: 1.0649x; 1.0189x over previous
//
#include <hip/hip_runtime.h>

constexpr int HW = 1024 * 1024;
constexpr int NB = 16;
constexpr float EPS = 1e-6f;
constexpr int BLOCKS_PER_BATCH = 256;  // 4096 blocks total
constexpr int THREADS = 256;
constexpr int NVEC    = HW / 4;                      // 262144 vec4 per batch
constexpr int U       = NVEC / (BLOCKS_PER_BATCH * THREADS);  // 4 windows/thread
constexpr int CHUNK   = U * THREADS;                 // 1024 vec4 = 16 KB per block per stream
constexpr int NBLK    = NB * BLOCKS_PER_BATCH;       // 4096

typedef float f32x4 __attribute__((ext_vector_type(4)));
typedef int   i32x4 __attribute__((ext_vector_type(4)));

// Stage 1: per-block partials -> ws4[gid] = {Sp, Spp, St, Stp}. No atomics.
//
// R5 = R2 (best: nt + forced 12-deep pipeline, 3.75 TB/s) with ONE change:
// block-contiguous layout. Interleaved layout put each block's 12 in-flight
// loads in 36 widely-separated 4 KB regions (~50K active regions chip-wide
// >> HBM banks -> row-activate per 128B burst). Contiguous chunks put each
// block's in-flight set in 3 x 16 KB spans (1-2 DRAM rows per stream).
// R1 already "tested" this layout but was doubly confounded (collapsed
// pipeline VGPR=32 + L2-allocating loads); this is the valid cell.
__global__ __launch_bounds__(THREADS, 6) void dice_partial(
        const float* __restrict__ logits,
        const int*   __restrict__ labels,
        f32x4*       __restrict__ ws4) {
    const int b   = blockIdx.x >> 8;         // / BLOCKS_PER_BATCH
    const int blk = blockIdx.x & 255;        // % BLOCKS_PER_BATCH

    const f32x4* __restrict__ L0 = reinterpret_cast<const f32x4*>(logits + (size_t)b * 2 * HW);
    const f32x4* __restrict__ L1 = reinterpret_cast<const f32x4*>(logits + (size_t)b * 2 * HW + HW);
    const i32x4* __restrict__ LB = reinterpret_cast<const i32x4*>(labels + (size_t)b * HW);

    const int base = blk * CHUNK + threadIdx.x;   // contiguous 16 KB chunk per block

    // Issue all 12 loads, window-major (window stride = THREADS = 4 KB), so
    // consumption of window u proceeds at vmcnt(9/6/3/0) while later windows
    // stay in flight.
    f32x4 a0 = __builtin_nontemporal_load(&L0[base + 0 * THREADS]);
    f32x4 c0 = __builtin_nontemporal_load(&L1[base + 0 * THREADS]);
    i32x4 t0 = __builtin_nontemporal_load(&LB[base + 0 * THREADS]);
    f32x4 a1 = __builtin_nontemporal_load(&L0[base + 1 * THREADS]);
    f32x4 c1 = __builtin_nontemporal_load(&L1[base + 1 * THREADS]);
    i32x4 t1 = __builtin_nontemporal_load(&LB[base + 1 * THREADS]);
    f32x4 a2 = __builtin_nontemporal_load(&L0[base + 2 * THREADS]);
    f32x4 c2 = __builtin_nontemporal_load(&L1[base + 2 * THREADS]);
    i32x4 t2 = __builtin_nontemporal_load(&LB[base + 2 * THREADS]);
    f32x4 a3 = __builtin_nontemporal_load(&L0[base + 3 * THREADS]);
    f32x4 c3 = __builtin_nontemporal_load(&L1[base + 3 * THREADS]);
    i32x4 t3 = __builtin_nontemporal_load(&LB[base + 3 * THREADS]);
    __builtin_amdgcn_sched_barrier(0);   // loads may not sink past this point

    float sp = 0.f, spp = 0.f, st = 0.f, stp = 0.f;

    #define CONSUME(A, C, T)                                              \
        _Pragma("unroll")                                                 \
        for (int k = 0; k < 4; ++k) {                                     \
            const float p  = 1.f / (1.f + __expf((A)[k] - (C)[k]));       \
            const float tf = (float)(T)[k];                               \
            sp += p; spp = fmaf(p, p, spp); st += tf; stp = fmaf(tf, p, stp); \
        }

    CONSUME(a0, c0, t0)
    CONSUME(a1, c1, t1)
    CONSUME(a2, c2, t2)
    CONSUME(a3, c3, t3)
    #undef CONSUME

    // wave-64 shuffle reduction
    #pragma unroll
    for (int off = 32; off > 0; off >>= 1) {
        sp  += __shfl_down(sp,  off);
        spp += __shfl_down(spp, off);
        st  += __shfl_down(st,  off);
        stp += __shfl_down(stp, off);
    }

    __shared__ float red[4][4];   // [wave][component]
    const int wave = threadIdx.x >> 6;
    const int lane = threadIdx.x & 63;
    if (lane == 0) {
        red[wave][0] = sp; red[wave][1] = spp; red[wave][2] = st; red[wave][3] = stp;
    }
    __syncthreads();
    if (threadIdx.x == 0) {
        f32x4 r;
        r.x = red[0][0] + red[1][0] + red[2][0] + red[3][0];
        r.y = red[0][1] + red[1][1] + red[2][1] + red[3][1];
        r.z = red[0][2] + red[1][2] + red[2][2] + red[3][2];
        r.w = red[0][3] + red[1][3] + red[2][3] + red[3][3];
        ws4[blockIdx.x] = r;   // plain store, distinct slot per block
    }
}

// Stage 2 (merged): one block, 1024 threads = 16 waves; wave w folds batch w's
// 256 partials and computes its dice term; thread 0 then folds the 16 terms.
__global__ __launch_bounds__(1024) void dice_reduce(
        const f32x4* __restrict__ ws4,
        float*       __restrict__ out) {
    const int wave = threadIdx.x >> 6;   // 0..15 == batch index
    const int lane = threadIdx.x & 63;

    const f32x4* p = ws4 + wave * BLOCKS_PER_BATCH;
    f32x4 v = p[lane] + p[lane + 64] + p[lane + 128] + p[lane + 192];

    #pragma unroll
    for (int off = 32; off > 0; off >>= 1) {
        v.x += __shfl_down(v.x, off);
        v.y += __shfl_down(v.y, off);
        v.z += __shfl_down(v.z, off);
        v.w += __shfl_down(v.w, off);
    }

    __shared__ float terms[NB];
    if (lane == 0) {
        const float Sp  = v.x;
        const float Spp = v.y;
        const float St  = v.z;
        const float Stp = v.w;
        const float N = (float)HW;

        const float num1 = 2.f * Stp;
        const float den1 = Spp + St;
        const float num0 = 2.f * (N - St - Sp + Stp);
        const float den0 = (N - 2.f * Sp + Spp) + (N - St);

        terms[wave] = num0 / (den0 + EPS) + num1 / (den1 + EPS);
    }
    __syncthreads();
    if (threadIdx.x == 0) {
        float s = 0.f;
        #pragma unroll
        for (int i = 0; i < NB; ++i) s += terms[i];
        out[0] = 1.f - s / 32.f;
    }
}

extern "C" void kernel_launch(void* const* d_in, const int* in_sizes, int n_in,
                              void* d_out, int out_size, void* d_ws, size_t ws_size,
                              hipStream_t stream) {
    const float* logits = (const float*)d_in[0];
    const int*   labels = (const int*)d_in[1];
    float* out = (float*)d_out;
    f32x4* ws4 = (f32x4*)d_ws;                       // 4096 vec4 = 64 KB

    dice_partial<<<NBLK, THREADS, 0, stream>>>(logits, labels, ws4);
    dice_reduce<<<1, 1024, 0, stream>>>(ws4, out);
}